// Round 1
// baseline (782.853 us; speedup 1.0000x reference)
//
#include <hip/hip_runtime.h>
#include <hip/hip_bf16.h>

// Problem constants: B=4, S=2048, HIDDEN=2048, HEADS=16, R=128
#define NB 4
#define SEQ 2048
#define HID 2048

typedef short bf16x8 __attribute__((ext_vector_type(8)));
typedef float f32x4 __attribute__((ext_vector_type(4)));

__device__ __forceinline__ unsigned short f2b(float f) {
  union { float f; unsigned int u; } v; v.f = f;
  unsigned int r = v.u + 0x7fffu + ((v.u >> 16) & 1u);
  return (unsigned short)(r >> 16);
}
__device__ __forceinline__ float blo(unsigned int u) {
  union { unsigned int u; float f; } t; t.u = u << 16; return t.f;
}
__device__ __forceinline__ float bhi(unsigned int u) {
  union { unsigned int u; float f; } t; t.u = u & 0xffff0000u; return t.f;
}

__device__ __forceinline__ void gload_lds16(const unsigned short* g, unsigned short* l) {
  __builtin_amdgcn_global_load_lds(
      (const __attribute__((address_space(1))) unsigned int*)g,
      (__attribute__((address_space(3))) unsigned int*)l, 16, 0, 0);
}

// ---------------- fp32 -> bf16 convert, 8 elems/thread ----------------
__global__ __launch_bounds__(256) void convert_bf16(const float* __restrict__ X,
                                                    unsigned short* __restrict__ Y, int n8) {
  int stride = gridDim.x * 256;
  for (int i = blockIdx.x * 256 + threadIdx.x; i < n8; i += stride) {
    long o = (long)i * 8;
    float4 a = *(const float4*)(X + o);
    float4 b = *(const float4*)(X + o + 4);
    uint4 p;
    p.x = (unsigned)f2b(a.x) | ((unsigned)f2b(a.y) << 16);
    p.y = (unsigned)f2b(a.z) | ((unsigned)f2b(a.w) << 16);
    p.z = (unsigned)f2b(b.x) | ((unsigned)f2b(b.y) << 16);
    p.w = (unsigned)f2b(b.z) | ((unsigned)f2b(b.w) << 16);
    *(uint4*)(Y + o) = p;
  }
}

// ---------------- transpose + convert: Y[c][r] = bf16(X[r][c]) ----------------
__global__ __launch_bounds__(256) void transpose_conv(const float* __restrict__ X,
                                                      unsigned short* __restrict__ Y,
                                                      int R, int C) {
  __shared__ float T[64][65];
  int r0 = blockIdx.y * 64, c0 = blockIdx.x * 64;
  int tx = threadIdx.x & 63, ty = threadIdx.x >> 6;
#pragma unroll
  for (int i = 0; i < 16; ++i) {
    int r = ty + i * 4;
    T[r][tx] = X[(long)(r0 + r) * C + c0 + tx];
  }
  __syncthreads();
#pragma unroll
  for (int i = 0; i < 16; ++i) {
    int c = ty + i * 4;
    Y[(long)(c0 + c) * R + r0 + tx] = f2b(T[tx][c]);
  }
}

// ---------------- bias vector: c = wo_b, then c += wvs_b @ wo_w ----------------
__global__ void bias_init(const float* __restrict__ wo_b, float* __restrict__ c) {
  int j = blockIdx.x * 256 + threadIdx.x;
  c[j] = wo_b[j];
}
__global__ void bias_accum(const float* __restrict__ wvs_b, const float* __restrict__ wo_w,
                           float* __restrict__ c) {
  int j = blockIdx.x * 256 + threadIdx.x;
  int t0 = blockIdx.y * 128;
  float p = 0.f;
  for (int t = 0; t < 128; ++t) p += wvs_b[t0 + t] * wo_w[(long)(t0 + t) * HID + j];
  atomicAdd(&c[j], p);
}

// ---------------- rank-16 projection: Y[r][0..15] = X[r][:] @ W + b ----------------
__global__ __launch_bounds__(256) void proj16(const float* __restrict__ X,
                                              const float* __restrict__ W,
                                              const float* __restrict__ bv,
                                              float* __restrict__ Y, int rows) {
  __shared__ unsigned short Wl[HID * 16];  // W in bf16, 64 KiB
  int tid = threadIdx.x;
  for (int i = tid * 8; i < HID * 16; i += 256 * 8) {
    float4 a = *(const float4*)(W + i);
    float4 b = *(const float4*)(W + i + 4);
    uint4 p;
    p.x = (unsigned)f2b(a.x) | ((unsigned)f2b(a.y) << 16);
    p.y = (unsigned)f2b(a.z) | ((unsigned)f2b(a.w) << 16);
    p.z = (unsigned)f2b(b.x) | ((unsigned)f2b(b.y) << 16);
    p.w = (unsigned)f2b(b.z) | ((unsigned)f2b(b.w) << 16);
    *(uint4*)&Wl[i] = p;
  }
  __syncthreads();
  int lane = tid & 63, wave = tid >> 6;
  int rpb = rows / gridDim.x;
  int row0 = blockIdx.x * rpb + wave * (rpb >> 2);
  for (int r = row0; r < row0 + (rpb >> 2); ++r) {
    const float* xr = X + (long)r * HID;
    float acc[16];
#pragma unroll
    for (int h = 0; h < 16; ++h) acc[h] = 0.f;
#pragma unroll
    for (int c = 0; c < HID / 64; ++c) {
      float xv = xr[c * 64 + lane];
      const uint4* wp = (const uint4*)&Wl[(c * 64 + lane) * 16];
      uint4 w0 = wp[0], w1 = wp[1];
      acc[0]  += xv * blo(w0.x); acc[1]  += xv * bhi(w0.x);
      acc[2]  += xv * blo(w0.y); acc[3]  += xv * bhi(w0.y);
      acc[4]  += xv * blo(w0.z); acc[5]  += xv * bhi(w0.z);
      acc[6]  += xv * blo(w0.w); acc[7]  += xv * bhi(w0.w);
      acc[8]  += xv * blo(w1.x); acc[9]  += xv * bhi(w1.x);
      acc[10] += xv * blo(w1.y); acc[11] += xv * bhi(w1.y);
      acc[12] += xv * blo(w1.z); acc[13] += xv * bhi(w1.z);
      acc[14] += xv * blo(w1.w); acc[15] += xv * bhi(w1.w);
    }
#pragma unroll
    for (int h = 0; h < 16; ++h) {
#pragma unroll
      for (int m = 1; m < 64; m <<= 1) acc[h] += __shfl_xor(acc[h], m, 64);
    }
    if (lane == 0) {
#pragma unroll
      for (int h = 0; h < 16; ++h) Y[(long)r * 16 + h] = acc[h] + bv[h];
    }
  }
}

// ---------------- softmax over 2048 keys, rank-16 logits; P in bf16 ----------------
__global__ __launch_bounds__(256) void attn_softmax(const float* __restrict__ Qf,
                                                    const float* __restrict__ Kf,
                                                    unsigned short* __restrict__ P) {
  __shared__ unsigned short Kl[SEQ * 16];  // K_b in bf16, 64 KiB
  int b = blockIdx.y;
  const float* Kb = Kf + (long)b * SEQ * 16;
  int tid = threadIdx.x;
  for (int i = tid * 8; i < SEQ * 16; i += 256 * 8) {
    float4 a = *(const float4*)(Kb + i);
    float4 b4 = *(const float4*)(Kb + i + 4);
    uint4 p;
    p.x = (unsigned)f2b(a.x) | ((unsigned)f2b(a.y) << 16);
    p.y = (unsigned)f2b(a.z) | ((unsigned)f2b(a.w) << 16);
    p.z = (unsigned)f2b(b4.x) | ((unsigned)f2b(b4.y) << 16);
    p.w = (unsigned)f2b(b4.z) | ((unsigned)f2b(b4.w) << 16);
    *(uint4*)&Kl[i] = p;
  }
  __syncthreads();
  int lane = tid & 63, wave = tid >> 6;
  int q0 = blockIdx.x * 32 + wave * 8;
  const float scale = 0.08838834764831845f;  // 1/sqrt(128)
  for (int r = q0; r < q0 + 8; ++r) {
    const float* qp = Qf + ((long)b * SEQ + r) * 16;
    float qv[16];
#pragma unroll
    for (int h = 0; h < 16; h += 4) {
      float4 t = *(const float4*)(qp + h);
      qv[h] = t.x; qv[h + 1] = t.y; qv[h + 2] = t.z; qv[h + 3] = t.w;
    }
    float pv[32];
    float mx = -1e30f;
#pragma unroll
    for (int c = 0; c < 32; ++c) {
      const uint4* kp = (const uint4*)&Kl[(c * 64 + lane) * 16];
      uint4 k0 = kp[0], k1 = kp[1];
      float a = 0.f;
      a += qv[0]  * blo(k0.x) + qv[1]  * bhi(k0.x);
      a += qv[2]  * blo(k0.y) + qv[3]  * bhi(k0.y);
      a += qv[4]  * blo(k0.z) + qv[5]  * bhi(k0.z);
      a += qv[6]  * blo(k0.w) + qv[7]  * bhi(k0.w);
      a += qv[8]  * blo(k1.x) + qv[9]  * bhi(k1.x);
      a += qv[10] * blo(k1.y) + qv[11] * bhi(k1.y);
      a += qv[12] * blo(k1.z) + qv[13] * bhi(k1.z);
      a += qv[14] * blo(k1.w) + qv[15] * bhi(k1.w);
      pv[c] = a * scale;
      mx = fmaxf(mx, pv[c]);
    }
#pragma unroll
    for (int m = 1; m < 64; m <<= 1) mx = fmaxf(mx, __shfl_xor(mx, m, 64));
    float sum = 0.f;
#pragma unroll
    for (int c = 0; c < 32; ++c) { pv[c] = __expf(pv[c] - mx); sum += pv[c]; }
#pragma unroll
    for (int m = 1; m < 64; m <<= 1) sum += __shfl_xor(sum, m, 64);
    float inv = 1.f / sum;
    unsigned short* Pr = P + ((long)b * SEQ + r) * SEQ;
#pragma unroll
    for (int c = 0; c < 32; ++c) Pr[c * 64 + lane] = f2b(pv[c] * inv);
  }
}

// ---------------- bf16 MFMA GEMM, C[m][n] = sum_k A[m][k]*Bt[n][k] ----------------
// 128x128 tile, BK=64, 4 waves (2x2), m97-style global_load_lds staging.
// MODE 0: bf16 row-major out. MODE 1: bf16 out written TRANSPOSED per 2048-row batch
//         (VwT[b][n][m%2048]).  MODE 2: f32 out + bias[n].
template <int MODE>
__global__ __launch_bounds__(256, 2) void gemm_bt(const unsigned short* __restrict__ A,
                                                  const unsigned short* __restrict__ Bt,
                                                  void* __restrict__ Cv,
                                                  const float* __restrict__ bias,
                                                  int K, long sA, long sB, long sC, int ldc) {
  __shared__ unsigned short As[128 * 64];
  __shared__ unsigned short Bs[128 * 64];
  const int tid = threadIdx.x;
  const int lane = tid & 63, wave = tid >> 6;
  A += blockIdx.z * sA;
  Bt += blockIdx.z * sB;
  const long bm = (long)blockIdx.y * 128, bn = (long)blockIdx.x * 128;
  const int wm = (wave >> 1) * 64, wn = (wave & 1) * 64;
  f32x4 acc[4][4] = {};
  const unsigned short* gA = A + (bm + wave * 32 + (lane >> 3)) * (long)K + (lane & 7) * 8;
  const unsigned short* gB = Bt + (bn + wave * 32 + (lane >> 3)) * (long)K + (lane & 7) * 8;
  unsigned short* lA = &As[wave * 2048];
  unsigned short* lB = &Bs[wave * 2048];
  const int nkt = K >> 6;
  for (int kt = 0; kt < nkt; ++kt) {
    const unsigned short* ga = gA + kt * 64;
    const unsigned short* gb = gB + kt * 64;
#pragma unroll
    for (int c = 0; c < 4; ++c) {
      gload_lds16(ga + (long)c * 8 * K, lA + c * 512);
      gload_lds16(gb + (long)c * 8 * K, lB + c * 512);
    }
    __syncthreads();
#pragma unroll
    for (int ks = 0; ks < 2; ++ks) {
      bf16x8 af[4], bfr[4];
#pragma unroll
      for (int m = 0; m < 4; ++m)
        af[m] = *(const bf16x8*)&As[(wm + m * 16 + (lane & 15)) * 64 + ks * 32 + (lane >> 4) * 8];
#pragma unroll
      for (int n = 0; n < 4; ++n)
        bfr[n] = *(const bf16x8*)&Bs[(wn + n * 16 + (lane & 15)) * 64 + ks * 32 + (lane >> 4) * 8];
#pragma unroll
      for (int m = 0; m < 4; ++m)
#pragma unroll
        for (int n = 0; n < 4; ++n)
          acc[m][n] = __builtin_amdgcn_mfma_f32_16x16x32_bf16(af[m], bfr[n], acc[m][n], 0, 0, 0);
    }
    __syncthreads();
  }
  const int rg = (lane >> 4) * 4;
  const int ci = lane & 15;
#pragma unroll
  for (int m = 0; m < 4; ++m) {
#pragma unroll
    for (int n = 0; n < 4; ++n) {
      long gr0 = bm + wm + m * 16 + rg;
      long gc = bn + wn + n * 16 + ci;
      if (MODE == 0) {
        unsigned short* C = (unsigned short*)Cv;
#pragma unroll
        for (int i = 0; i < 4; ++i) C[(gr0 + i) * (long)ldc + gc] = f2b(acc[m][n][i]);
      } else if (MODE == 1) {
        unsigned short* C = (unsigned short*)Cv;
        long addr = (gr0 >> 11) * (long)(SEQ * HID) + gc * SEQ + (gr0 & 2047);
        ushort4 v;
        v.x = f2b(acc[m][n][0]); v.y = f2b(acc[m][n][1]);
        v.z = f2b(acc[m][n][2]); v.w = f2b(acc[m][n][3]);
        *(ushort4*)(C + addr) = v;
      } else {
        float* C = (float*)Cv + (long)blockIdx.z * sC;
        float bb = bias[gc];
#pragma unroll
        for (int i = 0; i < 4; ++i) C[(gr0 + i) * (long)ldc + gc] = acc[m][n][i] + bb;
      }
    }
  }
}

extern "C" void kernel_launch(void* const* d_in, const int* in_sizes, int n_in,
                              void* d_out, int out_size, void* d_ws, size_t ws_size,
                              hipStream_t stream) {
  (void)in_sizes; (void)n_in; (void)out_size; (void)ws_size;
  const float* q     = (const float*)d_in[0];
  const float* k     = (const float*)d_in[1];
  // d_in[2] = v : unused by the reference (V is projected from k)
  const float* wqs_w = (const float*)d_in[3];
  const float* wqs_b = (const float*)d_in[4];
  const float* wks_w = (const float*)d_in[5];
  const float* wks_b = (const float*)d_in[6];
  const float* wvs_w = (const float*)d_in[7];
  const float* wvs_b = (const float*)d_in[8];
  const float* wo_w  = (const float*)d_in[9];
  const float* wo_b  = (const float*)d_in[10];

  char* ws = (char*)d_ws;
  const long MB = 1048576;
  // Workspace layout (74 MB total, with liveness-safe aliasing):
  float* Qf            = (float*)(ws);                         // [8192,16] f32
  float* Kf            = (float*)(ws + 524288);                // [8192,16] f32
  float* cvec          = (float*)(ws + MB);                    // [2048] f32
  unsigned short* kbf  = (unsigned short*)(ws + 2 * MB);       // 2..34 MB  k in bf16
  unsigned short* P    = kbf;                                  // alias: kbf dead after Vw GEMM
  unsigned short* VwT  = (unsigned short*)(ws + 34 * MB);      // 34..66 MB
  unsigned short* wvsbf= VwT;                                  // alias: dead before VwT written
  unsigned short* woT  = (unsigned short*)(ws + 42 * MB);      // alias inside VwT region
  unsigned short* W2T  = (unsigned short*)(ws + 66 * MB);      // 66..74 MB

  // 1) converts
  convert_bf16<<<2048, 256, 0, stream>>>(k, kbf, (NB * SEQ * HID) / 8);
  convert_bf16<<<2048, 256, 0, stream>>>(wvs_w, wvsbf, (HID * HID) / 8);
  transpose_conv<<<dim3(32, 32), 256, 0, stream>>>(wo_w, woT, HID, HID);
  // 2) fused bias c = wvs_b @ wo_w + wo_b
  bias_init<<<8, 256, 0, stream>>>(wo_b, cvec);
  bias_accum<<<dim3(8, 16), 256, 0, stream>>>(wvs_b, wo_w, cvec);
  // 3) rank-16 projections Q, K
  proj16<<<512, 256, 0, stream>>>(q, wqs_w, wqs_b, Qf, NB * SEQ);
  proj16<<<512, 256, 0, stream>>>(k, wks_w, wks_b, Kf, NB * SEQ);
  // 4) W2T[j][i] = (wvs_w @ wo_w)^T in bf16
  gemm_bt<0><<<dim3(16, 16, 1), 256, 0, stream>>>(woT, wvsbf, W2T, nullptr, HID, 0, 0, 0, HID);
  // 5) VwT[b][j][s] = (k @ W2)^T per batch, bf16 (transposed write)
  gemm_bt<1><<<dim3(16, 64, 1), 256, 0, stream>>>(kbf, W2T, VwT, nullptr, HID, 0, 0, 0, 0);
  // 6) P = softmax(Q K^T / sqrt(128)) in bf16
  attn_softmax<<<dim3(64, NB), 256, 0, stream>>>(Qf, Kf, P);
  // 7) out = P @ Vw + c  (f32)
  gemm_bt<2><<<dim3(16, 16, NB), 256, 0, stream>>>(P, VwT, d_out, cvec, SEQ,
                                                   (long)SEQ * SEQ, (long)SEQ * HID,
                                                   (long)SEQ * HID, HID);
}

// Round 3
// 538.250 us; speedup vs baseline: 1.4544x; 1.4544x over previous
//
#include <hip/hip_runtime.h>
#include <hip/hip_bf16.h>

// Problem constants: B=4, S=2048, HIDDEN=2048, HEADS=16, R=128
#define NB 4
#define SEQ 2048
#define HID 2048

typedef short bf16x8 __attribute__((ext_vector_type(8)));
typedef float f32x4 __attribute__((ext_vector_type(4)));

__device__ __forceinline__ unsigned short f2b(float f) {
  union { float f; unsigned int u; } v; v.f = f;
  unsigned int r = v.u + 0x7fffu + ((v.u >> 16) & 1u);
  return (unsigned short)(r >> 16);
}
__device__ __forceinline__ float blo(unsigned int u) {
  union { unsigned int u; float f; } t; t.u = u << 16; return t.f;
}
__device__ __forceinline__ float bhi(unsigned int u) {
  union { unsigned int u; float f; } t; t.u = u & 0xffff0000u; return t.f;
}

__device__ __forceinline__ void gload_lds16(const unsigned short* g, unsigned short* l) {
  __builtin_amdgcn_global_load_lds(
      (const __attribute__((address_space(1))) unsigned int*)g,
      (__attribute__((address_space(3))) unsigned int*)l, 16, 0, 0);
}

// ---------------- fp32 -> bf16 convert, 8 elems/thread ----------------
__global__ __launch_bounds__(256) void convert_bf16(const float* __restrict__ X,
                                                    unsigned short* __restrict__ Y, int n8) {
  int stride = gridDim.x * 256;
  for (int i = blockIdx.x * 256 + threadIdx.x; i < n8; i += stride) {
    long o = (long)i * 8;
    float4 a = *(const float4*)(X + o);
    float4 b = *(const float4*)(X + o + 4);
    uint4 p;
    p.x = (unsigned)f2b(a.x) | ((unsigned)f2b(a.y) << 16);
    p.y = (unsigned)f2b(a.z) | ((unsigned)f2b(a.w) << 16);
    p.z = (unsigned)f2b(b.x) | ((unsigned)f2b(b.y) << 16);
    p.w = (unsigned)f2b(b.z) | ((unsigned)f2b(b.w) << 16);
    *(uint4*)(Y + o) = p;
  }
}

// ---------------- transpose + convert: Y[c][r] = bf16(X[r][c]) ----------------
__global__ __launch_bounds__(256) void transpose_conv(const float* __restrict__ X,
                                                      unsigned short* __restrict__ Y,
                                                      int R, int C) {
  __shared__ float T[64][65];
  int r0 = blockIdx.y * 64, c0 = blockIdx.x * 64;
  int tx = threadIdx.x & 63, ty = threadIdx.x >> 6;
#pragma unroll
  for (int i = 0; i < 16; ++i) {
    int r = ty + i * 4;
    T[r][tx] = X[(long)(r0 + r) * C + c0 + tx];
  }
  __syncthreads();
#pragma unroll
  for (int i = 0; i < 16; ++i) {
    int c = ty + i * 4;
    Y[(long)(c0 + c) * R + r0 + tx] = f2b(T[tx][c]);
  }
}

// ---------------- W [2048][16] -> WT bf16 [16][2048] ----------------
__global__ __launch_bounds__(256) void wt_prep(const float* __restrict__ W,
                                               unsigned short* __restrict__ WT) {
  __shared__ float T[16][17];
  int t = threadIdx.x;
  int k0 = blockIdx.x * 16;
  T[t >> 4][t & 15] = W[k0 * 16 + t];
  __syncthreads();
  int h = t >> 4, kk = t & 15;
  WT[h * 2048 + k0 + kk] = f2b(T[kk][h]);
}

// ---------------- bias vector: c = wo_b, then c += wvs_b @ wo_w ----------------
__global__ void bias_init(const float* __restrict__ wo_b, float* __restrict__ c) {
  int j = blockIdx.x * 256 + threadIdx.x;
  c[j] = wo_b[j];
}
__global__ void bias_accum(const float* __restrict__ wvs_b, const float* __restrict__ wo_w,
                           float* __restrict__ c) {
  int j = blockIdx.x * 256 + threadIdx.x;
  int t0 = blockIdx.y * 128;
  float p = 0.f;
  for (int t = 0; t < 128; ++t) p += wvs_b[t0 + t] * wo_w[(long)(t0 + t) * HID + j];
  atomicAdd(&c[j], p);
}

// ---------------- rank-16 projection via MFMA ----------------
// M=8192, N=16, K=2048. Block = 64 rows, BK=256. 4 waves, each wave owns 16 rows.
// Fuses k -> bf16 conversion (kbf) on the y==1 path.
__global__ __launch_bounds__(256) void proj_mfma(
    const float* __restrict__ Xq, const float* __restrict__ Xk,
    const unsigned short* __restrict__ WTq, const unsigned short* __restrict__ WTk,
    const float* __restrict__ bq, const float* __restrict__ bk,
    float* __restrict__ Yq, float* __restrict__ Yk,
    unsigned short* __restrict__ kbf) {
  __shared__ unsigned short Xs[64 * 256];  // 32 KiB, XOR-swizzled rows of 512B
  const int tid = threadIdx.x;
  const int lane = tid & 63, wave = tid >> 6;
  const bool isK = (blockIdx.y == 1);
  const float* X = isK ? Xk : Xq;
  const unsigned short* WT = isK ? WTk : WTq;
  const float* bias = isK ? bk : bq;
  float* Y = isK ? Yk : Yq;
  const long row0 = (long)blockIdx.x * 64;
  const float* Xb = X + row0 * HID;

  f32x4 acc = {0.f, 0.f, 0.f, 0.f};
  float4 regs[16];
  // prologue: load chunk 0 (each thread: 16 coalesced float4, 16B/lane)
#pragma unroll
  for (int i = 0; i < 16; ++i)
    regs[i] = *(const float4*)(Xb + (long)(i * 4 + wave) * HID + lane * 4);

  const int arow = wave * 16 + (lane & 15);
  const int rowb = arow * 512;
  const int swzA = (arow & 7) << 4;
  const int g16 = (lane >> 4) * 16;

  for (int c = 0; c < 8; ++c) {
    // convert to bf16
    ushort4 cv[16];
#pragma unroll
    for (int i = 0; i < 16; ++i) {
      cv[i].x = f2b(regs[i].x); cv[i].y = f2b(regs[i].y);
      cv[i].z = f2b(regs[i].z); cv[i].w = f2b(regs[i].w);
    }
    // swizzled LDS write (8B per thread per i; 2-way bank alias = free)
#pragma unroll
    for (int i = 0; i < 16; ++i) {
      int r = i * 4 + wave;
      int b = r * 512 + ((lane * 8) ^ ((r & 7) << 4));
      *(ushort4*)((char*)Xs + b) = cv[i];
    }
    // fused bf16 k output
    if (isK) {
#pragma unroll
      for (int i = 0; i < 16; ++i)
        *(ushort4*)(kbf + (row0 + i * 4 + wave) * (long)HID + c * 256 + lane * 4) = cv[i];
    }
    __syncthreads();
    // prefetch next chunk while MFMA phase runs
    if (c < 7) {
#pragma unroll
      for (int i = 0; i < 16; ++i)
        regs[i] = *(const float4*)(Xb + (long)(i * 4 + wave) * HID + (c + 1) * 256 + lane * 4);
    }
    // MFMA over this chunk: 8 x (16x16x32)
    const unsigned short* WTc = WT + (lane & 15) * 2048 + c * 256 + (lane >> 4) * 8;
#pragma unroll
    for (int kk = 0; kk < 8; ++kk) {
      int b = rowb + ((kk * 64 + g16) ^ swzA);
      bf16x8 af = *(const bf16x8*)((const char*)Xs + b);
      bf16x8 wf = *(const bf16x8*)(WTc + kk * 32);
      acc = __builtin_amdgcn_mfma_f32_16x16x32_bf16(af, wf, acc, 0, 0, 0);
    }
    __syncthreads();
  }
  // epilogue: C mapping col=lane&15, row=(lane>>4)*4+i
  const int ci = lane & 15;
  const int rg = (lane >> 4) * 4;
  float bb = bias[ci];
#pragma unroll
  for (int i = 0; i < 4; ++i) {
    long r = row0 + wave * 16 + rg + i;
    Y[r * 16 + ci] = acc[i] + bb;
  }
}

// ---------------- softmax over 2048 keys, rank-16 logits; P in bf16 ----------------
__global__ __launch_bounds__(256) void attn_softmax(const float* __restrict__ Qf,
                                                    const float* __restrict__ Kf,
                                                    unsigned short* __restrict__ P) {
  __shared__ unsigned short Kl[SEQ * 16];  // K_b in bf16, 64 KiB
  int b = blockIdx.y;
  const float* Kb = Kf + (long)b * SEQ * 16;
  int tid = threadIdx.x;
  for (int i = tid * 8; i < SEQ * 16; i += 256 * 8) {
    float4 a = *(const float4*)(Kb + i);
    float4 b4 = *(const float4*)(Kb + i + 4);
    uint4 p;
    p.x = (unsigned)f2b(a.x) | ((unsigned)f2b(a.y) << 16);
    p.y = (unsigned)f2b(a.z) | ((unsigned)f2b(a.w) << 16);
    p.z = (unsigned)f2b(b4.x) | ((unsigned)f2b(b4.y) << 16);
    p.w = (unsigned)f2b(b4.z) | ((unsigned)f2b(b4.w) << 16);
    *(uint4*)&Kl[i] = p;
  }
  __syncthreads();
  int lane = tid & 63, wave = tid >> 6;
  int q0 = blockIdx.x * 32 + wave * 8;
  const float scale = 0.08838834764831845f;  // 1/sqrt(128)
  for (int r = q0; r < q0 + 8; ++r) {
    const float* qp = Qf + ((long)b * SEQ + r) * 16;
    float qv[16];
#pragma unroll
    for (int h = 0; h < 16; h += 4) {
      float4 t = *(const float4*)(qp + h);
      qv[h] = t.x; qv[h + 1] = t.y; qv[h + 2] = t.z; qv[h + 3] = t.w;
    }
    float pv[32];
    float mx = -1e30f;
#pragma unroll
    for (int c = 0; c < 32; ++c) {
      const uint4* kp = (const uint4*)&Kl[(c * 64 + lane) * 16];
      uint4 k0 = kp[0], k1 = kp[1];
      float a = 0.f;
      a += qv[0]  * blo(k0.x) + qv[1]  * bhi(k0.x);
      a += qv[2]  * blo(k0.y) + qv[3]  * bhi(k0.y);
      a += qv[4]  * blo(k0.z) + qv[5]  * bhi(k0.z);
      a += qv[6]  * blo(k0.w) + qv[7]  * bhi(k0.w);
      a += qv[8]  * blo(k1.x) + qv[9]  * bhi(k1.x);
      a += qv[10] * blo(k1.y) + qv[11] * bhi(k1.y);
      a += qv[12] * blo(k1.z) + qv[13] * bhi(k1.z);
      a += qv[14] * blo(k1.w) + qv[15] * bhi(k1.w);
      pv[c] = a * scale;
      mx = fmaxf(mx, pv[c]);
    }
#pragma unroll
    for (int m = 1; m < 64; m <<= 1) mx = fmaxf(mx, __shfl_xor(mx, m, 64));
    float sum = 0.f;
#pragma unroll
    for (int c = 0; c < 32; ++c) { pv[c] = __expf(pv[c] - mx); sum += pv[c]; }
#pragma unroll
    for (int m = 1; m < 64; m <<= 1) sum += __shfl_xor(sum, m, 64);
    float inv = 1.f / sum;
    unsigned short* Pr = P + ((long)b * SEQ + r) * SEQ;
#pragma unroll
    for (int c = 0; c < 32; ++c) Pr[c * 64 + lane] = f2b(pv[c] * inv);
  }
}

// ---------------- bf16 MFMA GEMM, C[m][n] = sum_k A[m][k]*Bt[n][k] ----------------
// 128x128 tile, BK=64, 4 waves (2x2), m97-style global_load_lds staging.
// MODE 0: bf16 row-major out. MODE 1: bf16 out written TRANSPOSED per 2048-row batch
//         (VwT[b][n][m%2048]).  MODE 2: f32 out + bias[n].
template <int MODE>
__global__ __launch_bounds__(256, 2) void gemm_bt(const unsigned short* __restrict__ A,
                                                  const unsigned short* __restrict__ Bt,
                                                  void* __restrict__ Cv,
                                                  const float* __restrict__ bias,
                                                  int K, long sA, long sB, long sC, int ldc) {
  __shared__ unsigned short As[128 * 64];
  __shared__ unsigned short Bs[128 * 64];
  const int tid = threadIdx.x;
  const int lane = tid & 63, wave = tid >> 6;
  A += blockIdx.z * sA;
  Bt += blockIdx.z * sB;
  const long bm = (long)blockIdx.y * 128, bn = (long)blockIdx.x * 128;
  const int wm = (wave >> 1) * 64, wn = (wave & 1) * 64;
  f32x4 acc[4][4] = {};
  const unsigned short* gA = A + (bm + wave * 32 + (lane >> 3)) * (long)K + (lane & 7) * 8;
  const unsigned short* gB = Bt + (bn + wave * 32 + (lane >> 3)) * (long)K + (lane & 7) * 8;
  unsigned short* lA = &As[wave * 2048];
  unsigned short* lB = &Bs[wave * 2048];
  const int nkt = K >> 6;
  for (int kt = 0; kt < nkt; ++kt) {
    const unsigned short* ga = gA + kt * 64;
    const unsigned short* gb = gB + kt * 64;
#pragma unroll
    for (int c = 0; c < 4; ++c) {
      gload_lds16(ga + (long)c * 8 * K, lA + c * 512);
      gload_lds16(gb + (long)c * 8 * K, lB + c * 512);
    }
    __syncthreads();
#pragma unroll
    for (int ks = 0; ks < 2; ++ks) {
      bf16x8 af[4], bfr[4];
#pragma unroll
      for (int m = 0; m < 4; ++m)
        af[m] = *(const bf16x8*)&As[(wm + m * 16 + (lane & 15)) * 64 + ks * 32 + (lane >> 4) * 8];
#pragma unroll
      for (int n = 0; n < 4; ++n)
        bfr[n] = *(const bf16x8*)&Bs[(wn + n * 16 + (lane & 15)) * 64 + ks * 32 + (lane >> 4) * 8];
#pragma unroll
      for (int m = 0; m < 4; ++m)
#pragma unroll
        for (int n = 0; n < 4; ++n)
          acc[m][n] = __builtin_amdgcn_mfma_f32_16x16x32_bf16(af[m], bfr[n], acc[m][n], 0, 0, 0);
    }
    __syncthreads();
  }
  const int rg = (lane >> 4) * 4;
  const int ci = lane & 15;
#pragma unroll
  for (int m = 0; m < 4; ++m) {
#pragma unroll
    for (int n = 0; n < 4; ++n) {
      long gr0 = bm + wm + m * 16 + rg;
      long gc = bn + wn + n * 16 + ci;
      if (MODE == 0) {
        unsigned short* C = (unsigned short*)Cv;
#pragma unroll
        for (int i = 0; i < 4; ++i) C[(gr0 + i) * (long)ldc + gc] = f2b(acc[m][n][i]);
      } else if (MODE == 1) {
        unsigned short* C = (unsigned short*)Cv;
        long addr = (gr0 >> 11) * (long)(SEQ * HID) + gc * SEQ + (gr0 & 2047);
        ushort4 v;
        v.x = f2b(acc[m][n][0]); v.y = f2b(acc[m][n][1]);
        v.z = f2b(acc[m][n][2]); v.w = f2b(acc[m][n][3]);
        *(ushort4*)(C + addr) = v;
      } else {
        float* C = (float*)Cv + (long)blockIdx.z * sC;
        float bb = bias[gc];
#pragma unroll
        for (int i = 0; i < 4; ++i) C[(gr0 + i) * (long)ldc + gc] = acc[m][n][i] + bb;
      }
    }
  }
}

extern "C" void kernel_launch(void* const* d_in, const int* in_sizes, int n_in,
                              void* d_out, int out_size, void* d_ws, size_t ws_size,
                              hipStream_t stream) {
  (void)in_sizes; (void)n_in; (void)out_size; (void)ws_size;
  const float* q     = (const float*)d_in[0];
  const float* k     = (const float*)d_in[1];
  // d_in[2] = v : unused by the reference (V is projected from k)
  const float* wqs_w = (const float*)d_in[3];
  const float* wqs_b = (const float*)d_in[4];
  const float* wks_w = (const float*)d_in[5];
  const float* wks_b = (const float*)d_in[6];
  const float* wvs_w = (const float*)d_in[7];
  const float* wvs_b = (const float*)d_in[8];
  const float* wo_w  = (const float*)d_in[9];
  const float* wo_b  = (const float*)d_in[10];

  char* ws = (char*)d_ws;
  const long MB = 1048576;
  const long KB = 1024;
  // Workspace layout (74 MB total, with liveness-safe aliasing):
  float* Qf            = (float*)(ws);                         // [8192,16] f32
  float* Kf            = (float*)(ws + 512 * KB);              // [8192,16] f32
  float* cvec          = (float*)(ws + MB);                    // [2048] f32
  unsigned short* WTq  = (unsigned short*)(ws + MB + 64 * KB); // [16,2048] bf16
  unsigned short* WTk  = (unsigned short*)(ws + MB + 128 * KB);// [16,2048] bf16
  unsigned short* kbf  = (unsigned short*)(ws + 2 * MB);       // 2..34 MB  k in bf16
  unsigned short* P    = kbf;                                  // alias: kbf dead after Vw GEMM
  unsigned short* VwT  = (unsigned short*)(ws + 34 * MB);      // 34..66 MB
  unsigned short* wvsbf= VwT;                                  // alias: dead before VwT written
  unsigned short* woT  = (unsigned short*)(ws + 42 * MB);      // alias inside VwT region
  unsigned short* W2T  = (unsigned short*)(ws + 66 * MB);      // 66..74 MB

  // 1) W transposes for the rank-16 projections
  wt_prep<<<128, 256, 0, stream>>>(wqs_w, WTq);
  wt_prep<<<128, 256, 0, stream>>>(wks_w, WTk);
  // 2) rank-16 projections Q,K via MFMA; fuses k -> bf16 (kbf)
  proj_mfma<<<dim3(128, 2), 256, 0, stream>>>(q, k, WTq, WTk, wqs_b, wks_b, Qf, Kf, kbf);
  // 3) converts for the fused V/O weight
  convert_bf16<<<2048, 256, 0, stream>>>(wvs_w, wvsbf, (HID * HID) / 8);
  transpose_conv<<<dim3(32, 32), 256, 0, stream>>>(wo_w, woT, HID, HID);
  // 4) fused bias c = wvs_b @ wo_w + wo_b
  bias_init<<<8, 256, 0, stream>>>(wo_b, cvec);
  bias_accum<<<dim3(8, 16), 256, 0, stream>>>(wvs_b, wo_w, cvec);
  // 5) W2T[j][i] = (wvs_w @ wo_w)^T in bf16
  gemm_bt<0><<<dim3(16, 16, 1), 256, 0, stream>>>(woT, wvsbf, W2T, nullptr, HID, 0, 0, 0, HID);
  // 6) VwT[b][j][s] = (k @ W2)^T per batch, bf16 (transposed write)
  gemm_bt<1><<<dim3(16, 64, 1), 256, 0, stream>>>(kbf, W2T, VwT, nullptr, HID, 0, 0, 0, 0);
  // 7) P = softmax(Q K^T / sqrt(128)) in bf16  (P aliases kbf; runs after step 6)
  attn_softmax<<<dim3(64, NB), 256, 0, stream>>>(Qf, Kf, P);
  // 8) out = P @ Vw + c  (f32)
  gemm_bt<2><<<dim3(16, 16, NB), 256, 0, stream>>>(P, VwT, d_out, cvec, SEQ,
                                                   (long)SEQ * SEQ, (long)SEQ * HID,
                                                   (long)SEQ * HID, HID);
}

// Round 4
// 494.710 us; speedup vs baseline: 1.5824x; 1.0880x over previous
//
#include <hip/hip_runtime.h>
#include <hip/hip_bf16.h>

// Problem constants: B=4, S=2048, HIDDEN=2048, HEADS=16, R=128
#define NB 4
#define SEQ 2048
#define HID 2048

typedef short bf16x8 __attribute__((ext_vector_type(8)));
typedef float f32x4 __attribute__((ext_vector_type(4)));

__device__ __forceinline__ unsigned short f2b(float f) {
  union { float f; unsigned int u; } v; v.f = f;
  unsigned int r = v.u + 0x7fffu + ((v.u >> 16) & 1u);
  return (unsigned short)(r >> 16);
}
__device__ __forceinline__ float blo(unsigned int u) {
  union { unsigned int u; float f; } t; t.u = u << 16; return t.f;
}
__device__ __forceinline__ float bhi(unsigned int u) {
  union { unsigned int u; float f; } t; t.u = u & 0xffff0000u; return t.f;
}

__device__ __forceinline__ void gload_lds16(const unsigned short* g, unsigned short* l) {
  __builtin_amdgcn_global_load_lds(
      (const __attribute__((address_space(1))) unsigned int*)g,
      (__attribute__((address_space(3))) unsigned int*)l, 16, 0, 0);
}

// ---------------- fp32 -> bf16 convert, 8 elems/thread ----------------
__global__ __launch_bounds__(256) void convert_bf16(const float* __restrict__ X,
                                                    unsigned short* __restrict__ Y, int n8) {
  int stride = gridDim.x * 256;
  for (int i = blockIdx.x * 256 + threadIdx.x; i < n8; i += stride) {
    long o = (long)i * 8;
    float4 a = *(const float4*)(X + o);
    float4 b = *(const float4*)(X + o + 4);
    uint4 p;
    p.x = (unsigned)f2b(a.x) | ((unsigned)f2b(a.y) << 16);
    p.y = (unsigned)f2b(a.z) | ((unsigned)f2b(a.w) << 16);
    p.z = (unsigned)f2b(b.x) | ((unsigned)f2b(b.y) << 16);
    p.w = (unsigned)f2b(b.z) | ((unsigned)f2b(b.w) << 16);
    *(uint4*)(Y + o) = p;
  }
}

// ---------------- transpose + convert: Y[c][r] = bf16(X[r][c]) ----------------
__global__ __launch_bounds__(256) void transpose_conv(const float* __restrict__ X,
                                                      unsigned short* __restrict__ Y,
                                                      int R, int C) {
  __shared__ float T[64][65];
  int r0 = blockIdx.y * 64, c0 = blockIdx.x * 64;
  int tx = threadIdx.x & 63, ty = threadIdx.x >> 6;
#pragma unroll
  for (int i = 0; i < 16; ++i) {
    int r = ty + i * 4;
    T[r][tx] = X[(long)(r0 + r) * C + c0 + tx];
  }
  __syncthreads();
#pragma unroll
  for (int i = 0; i < 16; ++i) {
    int c = ty + i * 4;
    Y[(long)(c0 + c) * R + r0 + tx] = f2b(T[tx][c]);
  }
}

// ---------------- W [2048][16] -> WT bf16 [16][2048] ----------------
__global__ __launch_bounds__(256) void wt_prep(const float* __restrict__ W,
                                               unsigned short* __restrict__ WT) {
  __shared__ float T[16][17];
  int t = threadIdx.x;
  int k0 = blockIdx.x * 16;
  T[t >> 4][t & 15] = W[k0 * 16 + t];
  __syncthreads();
  int h = t >> 4, kk = t & 15;
  WT[h * 2048 + k0 + kk] = f2b(T[kk][h]);
}

// ---------------- bias vector: c = wo_b, then c += wvs_b @ wo_w ----------------
__global__ void bias_init(const float* __restrict__ wo_b, float* __restrict__ c) {
  int j = blockIdx.x * 256 + threadIdx.x;
  c[j] = wo_b[j];
}
__global__ void bias_accum(const float* __restrict__ wvs_b, const float* __restrict__ wo_w,
                           float* __restrict__ c) {
  int j = blockIdx.x * 256 + threadIdx.x;
  int t0 = blockIdx.y * 128;
  float p = 0.f;
  for (int t = 0; t < 128; ++t) p += wvs_b[t0 + t] * wo_w[(long)(t0 + t) * HID + j];
  atomicAdd(&c[j], p);
}

// ---------------- rank-16 projection via MFMA ----------------
__global__ __launch_bounds__(256) void proj_mfma(
    const float* __restrict__ Xq, const float* __restrict__ Xk,
    const unsigned short* __restrict__ WTq, const unsigned short* __restrict__ WTk,
    const float* __restrict__ bq, const float* __restrict__ bk,
    float* __restrict__ Yq, float* __restrict__ Yk,
    unsigned short* __restrict__ kbf) {
  __shared__ unsigned short Xs[64 * 256];  // 32 KiB, XOR-swizzled rows of 512B
  const int tid = threadIdx.x;
  const int lane = tid & 63, wave = tid >> 6;
  const bool isK = (blockIdx.y == 1);
  const float* X = isK ? Xk : Xq;
  const unsigned short* WT = isK ? WTk : WTq;
  const float* bias = isK ? bk : bq;
  float* Y = isK ? Yk : Yq;
  const long row0 = (long)blockIdx.x * 64;
  const float* Xb = X + row0 * HID;

  f32x4 acc = {0.f, 0.f, 0.f, 0.f};
  float4 regs[16];
#pragma unroll
  for (int i = 0; i < 16; ++i)
    regs[i] = *(const float4*)(Xb + (long)(i * 4 + wave) * HID + lane * 4);

  const int arow = wave * 16 + (lane & 15);
  const int rowb = arow * 512;
  const int swzA = (arow & 7) << 4;
  const int g16 = (lane >> 4) * 16;

  for (int c = 0; c < 8; ++c) {
    ushort4 cv[16];
#pragma unroll
    for (int i = 0; i < 16; ++i) {
      cv[i].x = f2b(regs[i].x); cv[i].y = f2b(regs[i].y);
      cv[i].z = f2b(regs[i].z); cv[i].w = f2b(regs[i].w);
    }
#pragma unroll
    for (int i = 0; i < 16; ++i) {
      int r = i * 4 + wave;
      int b = r * 512 + ((lane * 8) ^ ((r & 7) << 4));
      *(ushort4*)((char*)Xs + b) = cv[i];
    }
    if (isK) {
#pragma unroll
      for (int i = 0; i < 16; ++i)
        *(ushort4*)(kbf + (row0 + i * 4 + wave) * (long)HID + c * 256 + lane * 4) = cv[i];
    }
    __syncthreads();
    if (c < 7) {
#pragma unroll
      for (int i = 0; i < 16; ++i)
        regs[i] = *(const float4*)(Xb + (long)(i * 4 + wave) * HID + (c + 1) * 256 + lane * 4);
    }
    const unsigned short* WTc = WT + (lane & 15) * 2048 + c * 256 + (lane >> 4) * 8;
#pragma unroll
    for (int kk = 0; kk < 8; ++kk) {
      int b = rowb + ((kk * 64 + g16) ^ swzA);
      bf16x8 af = *(const bf16x8*)((const char*)Xs + b);
      bf16x8 wf = *(const bf16x8*)(WTc + kk * 32);
      acc = __builtin_amdgcn_mfma_f32_16x16x32_bf16(af, wf, acc, 0, 0, 0);
    }
    __syncthreads();
  }
  const int ci = lane & 15;
  const int rg = (lane >> 4) * 4;
  float bb = bias[ci];
#pragma unroll
  for (int i = 0; i < 4; ++i) {
    long r = row0 + wave * 16 + rg + i;
    Y[r * 16 + ci] = acc[i] + bb;
  }
}

// ---------------- softmax over 2048 keys, rank-16 logits; P in bf16 ----------------
__global__ __launch_bounds__(256) void attn_softmax(const float* __restrict__ Qf,
                                                    const float* __restrict__ Kf,
                                                    unsigned short* __restrict__ P) {
  __shared__ unsigned short Kl[SEQ * 16];  // K_b in bf16, 64 KiB
  int b = blockIdx.y;
  const float* Kb = Kf + (long)b * SEQ * 16;
  int tid = threadIdx.x;
  for (int i = tid * 8; i < SEQ * 16; i += 256 * 8) {
    float4 a = *(const float4*)(Kb + i);
    float4 b4 = *(const float4*)(Kb + i + 4);
    uint4 p;
    p.x = (unsigned)f2b(a.x) | ((unsigned)f2b(a.y) << 16);
    p.y = (unsigned)f2b(a.z) | ((unsigned)f2b(a.w) << 16);
    p.z = (unsigned)f2b(b4.x) | ((unsigned)f2b(b4.y) << 16);
    p.w = (unsigned)f2b(b4.z) | ((unsigned)f2b(b4.w) << 16);
    *(uint4*)&Kl[i] = p;
  }
  __syncthreads();
  int lane = tid & 63, wave = tid >> 6;
  int q0 = blockIdx.x * 32 + wave * 8;
  const float scale = 0.08838834764831845f;  // 1/sqrt(128)
  for (int r = q0; r < q0 + 8; ++r) {
    const float* qp = Qf + ((long)b * SEQ + r) * 16;
    float qv[16];
#pragma unroll
    for (int h = 0; h < 16; h += 4) {
      float4 t = *(const float4*)(qp + h);
      qv[h] = t.x; qv[h + 1] = t.y; qv[h + 2] = t.z; qv[h + 3] = t.w;
    }
    float pv[32];
    float mx = -1e30f;
#pragma unroll
    for (int c = 0; c < 32; ++c) {
      const uint4* kp = (const uint4*)&Kl[(c * 64 + lane) * 16];
      uint4 k0 = kp[0], k1 = kp[1];
      float a = 0.f;
      a += qv[0]  * blo(k0.x) + qv[1]  * bhi(k0.x);
      a += qv[2]  * blo(k0.y) + qv[3]  * bhi(k0.y);
      a += qv[4]  * blo(k0.z) + qv[5]  * bhi(k0.z);
      a += qv[6]  * blo(k0.w) + qv[7]  * bhi(k0.w);
      a += qv[8]  * blo(k1.x) + qv[9]  * bhi(k1.x);
      a += qv[10] * blo(k1.y) + qv[11] * bhi(k1.y);
      a += qv[12] * blo(k1.z) + qv[13] * bhi(k1.z);
      a += qv[14] * blo(k1.w) + qv[15] * bhi(k1.w);
      pv[c] = a * scale;
      mx = fmaxf(mx, pv[c]);
    }
#pragma unroll
    for (int m = 1; m < 64; m <<= 1) mx = fmaxf(mx, __shfl_xor(mx, m, 64));
    float sum = 0.f;
#pragma unroll
    for (int c = 0; c < 32; ++c) { pv[c] = __expf(pv[c] - mx); sum += pv[c]; }
#pragma unroll
    for (int m = 1; m < 64; m <<= 1) sum += __shfl_xor(sum, m, 64);
    float inv = 1.f / sum;
    unsigned short* Pr = P + ((long)b * SEQ + r) * SEQ;
#pragma unroll
    for (int c = 0; c < 32; ++c) Pr[c * 64 + lane] = f2b(pv[c] * inv);
  }
}

// ---------------- 128x128 MFMA GEMM (m97 structure) — used for W2 only ----------------
template <int MODE>
__global__ __launch_bounds__(256, 2) void gemm_bt(const unsigned short* __restrict__ A,
                                                  const unsigned short* __restrict__ Bt,
                                                  void* __restrict__ Cv,
                                                  const float* __restrict__ bias,
                                                  int K, long sA, long sB, long sC, int ldc) {
  __shared__ unsigned short As[128 * 64];
  __shared__ unsigned short Bs[128 * 64];
  const int tid = threadIdx.x;
  const int lane = tid & 63, wave = tid >> 6;
  A += blockIdx.z * sA;
  Bt += blockIdx.z * sB;
  const long bm = (long)blockIdx.y * 128, bn = (long)blockIdx.x * 128;
  const int wm = (wave >> 1) * 64, wn = (wave & 1) * 64;
  f32x4 acc[4][4] = {};
  const unsigned short* gA = A + (bm + wave * 32 + (lane >> 3)) * (long)K + (lane & 7) * 8;
  const unsigned short* gB = Bt + (bn + wave * 32 + (lane >> 3)) * (long)K + (lane & 7) * 8;
  unsigned short* lA = &As[wave * 2048];
  unsigned short* lB = &Bs[wave * 2048];
  const int nkt = K >> 6;
  for (int kt = 0; kt < nkt; ++kt) {
    const unsigned short* ga = gA + kt * 64;
    const unsigned short* gb = gB + kt * 64;
#pragma unroll
    for (int c = 0; c < 4; ++c) {
      gload_lds16(ga + (long)c * 8 * K, lA + c * 512);
      gload_lds16(gb + (long)c * 8 * K, lB + c * 512);
    }
    __syncthreads();
#pragma unroll
    for (int ks = 0; ks < 2; ++ks) {
      bf16x8 af[4], bfr[4];
#pragma unroll
      for (int m = 0; m < 4; ++m)
        af[m] = *(const bf16x8*)&As[(wm + m * 16 + (lane & 15)) * 64 + ks * 32 + (lane >> 4) * 8];
#pragma unroll
      for (int n = 0; n < 4; ++n)
        bfr[n] = *(const bf16x8*)&Bs[(wn + n * 16 + (lane & 15)) * 64 + ks * 32 + (lane >> 4) * 8];
#pragma unroll
      for (int m = 0; m < 4; ++m)
#pragma unroll
        for (int n = 0; n < 4; ++n)
          acc[m][n] = __builtin_amdgcn_mfma_f32_16x16x32_bf16(af[m], bfr[n], acc[m][n], 0, 0, 0);
    }
    __syncthreads();
  }
  const int rg = (lane >> 4) * 4;
  const int ci = lane & 15;
#pragma unroll
  for (int m = 0; m < 4; ++m) {
#pragma unroll
    for (int n = 0; n < 4; ++n) {
      long gr0 = bm + wm + m * 16 + rg;
      long gc = bn + wn + n * 16 + ci;
      if (MODE == 0) {
        unsigned short* C = (unsigned short*)Cv;
#pragma unroll
        for (int i = 0; i < 4; ++i) C[(gr0 + i) * (long)ldc + gc] = f2b(acc[m][n][i]);
      } else {
        float* C = (float*)Cv + (long)blockIdx.z * sC;
        float bb = bias[gc];
#pragma unroll
        for (int i = 0; i < 4; ++i) C[(gr0 + i) * (long)ldc + gc] = acc[m][n][i] + bb;
      }
    }
  }
}

// ---------------- 256x256 pipelined MFMA GEMM (T2+T4+T5) ----------------
// 8 waves (2M x 4N), BK=64, K-tile double-buffer, counted vmcnt(8), raw barriers.
// LDS layout: row-major 128B rows, 16B slots XOR-swizzled by (row&7); the global
// SOURCE address is pre-swizzled (rule 21) so global_load_lds writes linearly.
// MODE 1: bf16 out transposed per 2048-row batch. MODE 2: f32 out + bias.
template <int MODE>
__global__ __launch_bounds__(512, 2) void gemm256(const unsigned short* __restrict__ A,
                                                  const unsigned short* __restrict__ Bt,
                                                  void* __restrict__ Cv,
                                                  const float* __restrict__ bias,
                                                  int K, long sA, long sB, long sC, int ldc) {
  __shared__ unsigned short As[2][16384];
  __shared__ unsigned short Bs[2][16384];
  const int tid = threadIdx.x;
  const int lane = tid & 63, wave = tid >> 6;
  A += blockIdx.z * sA;
  Bt += blockIdx.z * sB;
  const long bm = (long)blockIdx.y * 256, bn = (long)blockIdx.x * 256;
  const int wrow = (wave >> 2) * 128;  // 2 M-groups of waves
  const int wcol = (wave & 3) * 64;    // 4 N-groups of waves

  // staging: instr j covers tile rows [j*64, j*64+64); thread -> row j*64+(tid>>3),
  // 16B slot (tid&7); source col pre-swizzled by (row&7) so LDS dest is linear.
  const int srow = tid >> 3;
  const int scol8 = ((tid & 7) ^ (srow & 7)) * 8;
  const unsigned short* gA = A + (bm + srow) * (long)K + scol8;
  const unsigned short* gB = Bt + (bn + srow) * (long)K + scol8;
  const int ldst = tid * 8;  // element offset inside each 8KB chunk

  // ds_read offsets: row r at byte r*128; slot addr XOR (r&7)<<4 (r&7 == lane&7)
  const int swz = (lane & 7) << 4;
  const int koff = (lane >> 4) * 16;
  const int arow_b = (wrow + (lane & 15)) * 128;
  const int brow_b = (wcol + (lane & 15)) * 128;

  f32x4 acc[8][4] = {};
  const int nt = K >> 6;

#define STAGE256(kt, buf)                                                          \
  {                                                                                \
    _Pragma("unroll") for (int j = 0; j < 4; ++j) {                                \
      gload_lds16(gA + (long)j * 64 * K + (kt) * 64, &As[buf][j * 4096 + ldst]);   \
      gload_lds16(gB + (long)j * 64 * K + (kt) * 64, &Bs[buf][j * 4096 + ldst]);   \
    }                                                                              \
  }

  STAGE256(0, 0);
  STAGE256(1, 1);
  asm volatile("s_waitcnt vmcnt(8)" ::: "memory");  // tile 0 landed (8 newest = tile 1)
  __builtin_amdgcn_s_barrier();

  int c = 0;
  for (int t = 0; t < nt; ++t) {
    const char* pa = (const char*)As[c];
    const char* pb = (const char*)Bs[c];
    bf16x8 a0[8], a1[8], b0[4], b1[4];
#pragma unroll
    for (int m = 0; m < 8; ++m) {
      int rb = arow_b + m * 2048;
      a0[m] = *(const bf16x8*)(pa + rb + ((koff) ^ swz));
      a1[m] = *(const bf16x8*)(pa + rb + ((64 + koff) ^ swz));
    }
#pragma unroll
    for (int n = 0; n < 4; ++n) {
      int rb = brow_b + n * 2048;
      b0[n] = *(const bf16x8*)(pb + rb + ((koff) ^ swz));
      b1[n] = *(const bf16x8*)(pb + rb + ((64 + koff) ^ swz));
    }
    // MFMA half 1 (ks=0) — overlaps ks=1 ds_reads via compiler lgkm scheduling
#pragma unroll
    for (int m = 0; m < 8; ++m)
#pragma unroll
      for (int n = 0; n < 4; ++n)
        acc[m][n] = __builtin_amdgcn_mfma_f32_16x16x32_bf16(a0[m], b0[n], acc[m][n], 0, 0, 0);
    // all our LDS reads done -> after block-wide barrier buf[c] is reusable
    asm volatile("s_waitcnt lgkmcnt(0)" ::: "memory");
    __builtin_amdgcn_s_barrier();
    if (t + 2 < nt) STAGE256(t + 2, c);
    // MFMA half 2 (ks=1): pure-register cluster; covers stage issue + load flight
    __builtin_amdgcn_s_setprio(1);
#pragma unroll
    for (int m = 0; m < 8; ++m)
#pragma unroll
      for (int n = 0; n < 4; ++n)
        acc[m][n] = __builtin_amdgcn_mfma_f32_16x16x32_bf16(a1[m], b1[n], acc[m][n], 0, 0, 0);
    __builtin_amdgcn_s_setprio(0);
    // counted wait: tile t+1's 8 loads are the oldest outstanding
    if (t + 2 < nt) {
      asm volatile("s_waitcnt vmcnt(8)" ::: "memory");
    } else {
      asm volatile("s_waitcnt vmcnt(0)" ::: "memory");
    }
    __builtin_amdgcn_s_barrier();
    c ^= 1;
  }
#undef STAGE256

  const int rg = (lane >> 4) * 4;
  const int ci = lane & 15;
#pragma unroll
  for (int m = 0; m < 8; ++m) {
#pragma unroll
    for (int n = 0; n < 4; ++n) {
      long gr0 = bm + wrow + m * 16 + rg;
      long gc = bn + wcol + n * 16 + ci;
      if (MODE == 1) {
        unsigned short* C = (unsigned short*)Cv;
        long addr = (gr0 >> 11) * (long)(SEQ * HID) + gc * SEQ + (gr0 & 2047);
        ushort4 v;
        v.x = f2b(acc[m][n][0]); v.y = f2b(acc[m][n][1]);
        v.z = f2b(acc[m][n][2]); v.w = f2b(acc[m][n][3]);
        *(ushort4*)(C + addr) = v;
      } else {
        float* C = (float*)Cv + (long)blockIdx.z * sC;
        float bb = bias[gc];
#pragma unroll
        for (int i = 0; i < 4; ++i) C[(gr0 + i) * (long)ldc + gc] = acc[m][n][i] + bb;
      }
    }
  }
}

extern "C" void kernel_launch(void* const* d_in, const int* in_sizes, int n_in,
                              void* d_out, int out_size, void* d_ws, size_t ws_size,
                              hipStream_t stream) {
  (void)in_sizes; (void)n_in; (void)out_size; (void)ws_size;
  const float* q     = (const float*)d_in[0];
  const float* k     = (const float*)d_in[1];
  // d_in[2] = v : unused by the reference (V is projected from k)
  const float* wqs_w = (const float*)d_in[3];
  const float* wqs_b = (const float*)d_in[4];
  const float* wks_w = (const float*)d_in[5];
  const float* wks_b = (const float*)d_in[6];
  const float* wvs_w = (const float*)d_in[7];
  const float* wvs_b = (const float*)d_in[8];
  const float* wo_w  = (const float*)d_in[9];
  const float* wo_b  = (const float*)d_in[10];

  char* ws = (char*)d_ws;
  const long MB = 1048576;
  const long KB = 1024;
  // Workspace layout (74 MB total, liveness-safe aliasing):
  float* Qf            = (float*)(ws);                         // [8192,16] f32
  float* Kf            = (float*)(ws + 512 * KB);              // [8192,16] f32
  float* cvec          = (float*)(ws + MB);                    // [2048] f32
  unsigned short* WTq  = (unsigned short*)(ws + MB + 64 * KB); // [16,2048] bf16
  unsigned short* WTk  = (unsigned short*)(ws + MB + 128 * KB);// [16,2048] bf16
  unsigned short* kbf  = (unsigned short*)(ws + 2 * MB);       // 2..34 MB  k in bf16
  unsigned short* P    = kbf;                                  // alias: kbf dead after Vw GEMM
  unsigned short* VwT  = (unsigned short*)(ws + 34 * MB);      // 34..66 MB
  unsigned short* wvsbf= VwT;                                  // alias: dead before VwT written
  unsigned short* woT  = (unsigned short*)(ws + 42 * MB);      // alias inside VwT region
  unsigned short* W2T  = (unsigned short*)(ws + 66 * MB);      // 66..74 MB

  // 1) W transposes for the rank-16 projections
  wt_prep<<<128, 256, 0, stream>>>(wqs_w, WTq);
  wt_prep<<<128, 256, 0, stream>>>(wks_w, WTk);
  // 2) rank-16 projections Q,K via MFMA; fuses k -> bf16 (kbf)
  proj_mfma<<<dim3(128, 2), 256, 0, stream>>>(q, k, WTq, WTk, wqs_b, wks_b, Qf, Kf, kbf);
  // 3) converts for the fused V/O weight
  convert_bf16<<<2048, 256, 0, stream>>>(wvs_w, wvsbf, (HID * HID) / 8);
  transpose_conv<<<dim3(32, 32), 256, 0, stream>>>(wo_w, woT, HID, HID);
  // 4) fused bias c = wvs_b @ wo_w + wo_b
  bias_init<<<8, 256, 0, stream>>>(wo_b, cvec);
  bias_accum<<<dim3(8, 16), 256, 0, stream>>>(wvs_b, wo_w, cvec);
  // 5) W2T[j][i] = (wvs_w @ wo_w)^T in bf16 (128^2 structure; 256-block grid)
  gemm_bt<0><<<dim3(16, 16, 1), 256, 0, stream>>>(woT, wvsbf, W2T, nullptr, HID, 0, 0, 0, HID);
  // 6) VwT[b][j][s] = (k @ W2)^T per batch, bf16 (256^2 pipelined, transposed write)
  gemm256<1><<<dim3(8, 32, 1), 512, 0, stream>>>(kbf, W2T, VwT, nullptr, HID, 0, 0, 0, 0);
  // 7) P = softmax(Q K^T / sqrt(128)) in bf16  (P aliases kbf; runs after step 6)
  attn_softmax<<<dim3(64, NB), 256, 0, stream>>>(Qf, Kf, P);
  // 8) out = P @ Vw + c  (f32, 256^2 pipelined)
  gemm256<2><<<dim3(8, 8, NB), 512, 0, stream>>>(P, VwT, d_out, cvec, SEQ,
                                                 (long)SEQ * SEQ, (long)SEQ * HID,
                                                 (long)SEQ * HID, HID);
}